// Round 4
// baseline (200.077 us; speedup 1.0000x reference)
//
#include <hip/hip_runtime.h>
#include <stdint.h>

#define NHEADS 16
#define DHEAD 64
#define SEQ 2048
#define BATCH 2
#define NINF 1024
#define NOUTF 1024
#define N3 3072
#define MTOT 4096  // BATCH*SEQ

typedef unsigned short US;
typedef __attribute__((ext_vector_type(8))) short short8;
typedef __attribute__((ext_vector_type(4))) short short4v;
typedef __attribute__((ext_vector_type(4))) float f32x4;

__device__ inline US f2bf(float f) {
  union { float f; unsigned u; } v; v.f = f;
  unsigned r = v.u + 0x7fffu + ((v.u >> 16) & 1u);
  return (US)(r >> 16);
}

__device__ inline f32x4 mfma16(short8 a, short8 b, f32x4 c) {
  return __builtin_amdgcn_mfma_f32_16x16x32_bf16(a, b, c, 0, 0, 0);
}

__device__ inline f32x4 mfma16k16(short4v a, short4v b, f32x4 c) {
  return __builtin_amdgcn_mfma_f32_16x16x16bf16_1k(a, b, c, 0, 0, 0);
}

__device__ inline void async16(const US* g, US* l) {
  __builtin_amdgcn_global_load_lds(
      (const __attribute__((address_space(1))) unsigned int*)g,
      (__attribute__((address_space(3))) unsigned int*)l, 16, 0, 0);
}

// fp32 -> bf16, 4 elements/thread
__global__ void k_convert(const float* __restrict__ src, US* __restrict__ dst, int n4) {
  int i = blockIdx.x * blockDim.x + threadIdx.x;
  if (i >= n4) return;
  float4 v = ((const float4*)src)[i];
  ushort4 o;
  o.x = f2bf(v.x); o.y = f2bf(v.y); o.z = f2bf(v.z); o.w = f2bf(v.w);
  ((ushort4*)dst)[i] = o;
}

// merged weight transpose: Wqkv [1024][3072] and Wff [1024][1024] -> bf16 [C][1024]
__global__ void k_wtrans(const float* __restrict__ Wqkv, const float* __restrict__ Wff,
                         US* __restrict__ dq, US* __restrict__ df) {
  __shared__ float tile[32][33];
  int bxi = blockIdx.x;
  const float* src; US* dst; int C;
  if (bxi < 96) { src = Wqkv; dst = dq; C = N3; }
  else          { src = Wff;  dst = df; C = NOUTF; bxi -= 96; }
  int bx = bxi * 32, by = blockIdx.y * 32;
  int tx = threadIdx.x, ty = threadIdx.y;
  for (int i = 0; i < 32; i += 8)
    tile[ty + i][tx] = src[(size_t)(by + ty + i) * C + bx + tx];
  __syncthreads();
  for (int i = 0; i < 32; i += 8)
    dst[(size_t)(bx + ty + i) * 1024 + by + tx] = f2bf(tile[tx][ty + i]);
}

// per-bh bf16 transpose: vbuf [bh][2048][64] -> vtbuf [bh][64][2048]
__global__ void k_vtrans(const US* __restrict__ src, US* __restrict__ dst) {
  __shared__ US tile[32][33];
  int bh = blockIdx.z;
  int bx = blockIdx.x * 32;  // d
  int by = blockIdx.y * 32;  // s
  int tx = threadIdx.x, ty = threadIdx.y;
  const US* s0 = src + (size_t)bh * SEQ * DHEAD;
  US* d0 = dst + (size_t)bh * DHEAD * SEQ;
  for (int i = 0; i < 32; i += 8)
    tile[ty + i][tx] = s0[(size_t)(by + ty + i) * DHEAD + bx + tx];
  __syncthreads();
  for (int i = 0; i < 32; i += 8)
    d0[(size_t)(bx + ty + i) * SEQ + by + tx] = tile[tx][ty + i];
}

// ---------------- qkv GEMM: 128x128 tile, m97 structure ----------------
// Q is pre-scaled by log2(e)/sqrt(DHEAD) so attention scores are directly
// exp2 exponents (deletes one v_mul per score in k_attn).
__global__ __launch_bounds__(256) void k_gemm_qkv(
    const US* __restrict__ A,   // [MTOT][NINF]
    const US* __restrict__ Bt,  // [N3][NINF]
    US* __restrict__ qbuf, US* __restrict__ kbuf, US* __restrict__ vbuf) {
  __shared__ US As[128 * 32];
  __shared__ US Bs[128 * 32];
  int tid = threadIdx.x;
  int wave = tid >> 6, lane = tid & 63, lm = lane & 15, lk = lane >> 4;
  int wm = wave >> 1, wn = wave & 1;
  int mbase = blockIdx.y * 128, nbase = blockIdx.x * 128;

  f32x4 acc[4][4];
#pragma unroll
  for (int i = 0; i < 4; ++i)
#pragma unroll
    for (int j = 0; j < 4; ++j) acc[i][j] = (f32x4){0.f, 0.f, 0.f, 0.f};

  const US* ga = A + (size_t)(mbase + (tid >> 2)) * NINF + (tid & 3) * 8;
  const US* gb = Bt + (size_t)(nbase + (tid >> 2)) * NINF + (tid & 3) * 8;
  US* la = As + tid * 8;
  US* lb = Bs + tid * 8;

  for (int kt = 0; kt < NINF / 32; ++kt) {
    int ko = kt * 32;
    async16(ga + ko, la);
    async16(ga + ko + (size_t)64 * NINF, la + 64 * 32);
    async16(gb + ko, lb);
    async16(gb + ko + (size_t)64 * NINF, lb + 64 * 32);
    __syncthreads();
    short8 a[4], b[4];
#pragma unroll
    for (int i = 0; i < 4; ++i)
      a[i] = *(const short8*)(As + (wm * 64 + i * 16 + lm) * 32 + lk * 8);
#pragma unroll
    for (int j = 0; j < 4; ++j)
      b[j] = *(const short8*)(Bs + (wn * 64 + j * 16 + lm) * 32 + lk * 8);
#pragma unroll
    for (int i = 0; i < 4; ++i)
#pragma unroll
      for (int j = 0; j < 4; ++j) acc[i][j] = mfma16(a[i], b[j], acc[i][j]);
    __syncthreads();
  }

  int which = nbase >> 10;  // 0=q 1=k 2=v (uniform per block)
  US* dsts = (which == 0) ? qbuf : (which == 1) ? kbuf : vbuf;
  float sc = (which == 0) ? 0.18033688011112042f : 1.f;  // log2(e)/8 folded into Q
#pragma unroll
  for (int j = 0; j < 4; ++j) {
    int col = nbase + wn * 64 + j * 16 + lm;
    int hh = (col & 1023) >> 6;
    int d = col & 63;
#pragma unroll
    for (int i = 0; i < 4; ++i) {
#pragma unroll
      for (int r = 0; r < 4; ++r) {
        int row = mbase + wm * 64 + i * 16 + lk * 4 + r;
        int bb = row >> 11;
        int s = row & (SEQ - 1);
        int bh = bb * NHEADS + hh;
        dsts[((size_t)bh * SEQ + s) * DHEAD + d] = f2bf(acc[i][j][r] * sc);
      }
    }
  }
}

// ---------------- attention v9: key-sliced waves ----------------
// v8 post-mortem: all 4 waves read the full 16KB K/V tile (64KB/block-tile)
// -> LDS pipe ~53% busy = tallest pole (MFMA pipe only 25%).
// v9: wave w owns key-group kg=w for ALL 64 q-rows (4 independent qg chains).
// Per tile each wave reads only its 2KB K slice + 2KB V slice: 16KB/block-tile,
// a 4x LDS-read cut. Rowsums move to VALU using the SAME half-up-rounded bf16
// bits the PV MFMA consumes (numerics identical to the ones-MFMA rowsum).
// Epilogue: 4-wave O-reduction through LDS (2 dg-half phases, 24KB region),
// racc reduced via LDS + shfl_xor over lk. Keeps v8's balanced round mapping,
// depth-2 dbuf + counted vmcnt(4), staging, swizzle. Adds setprio around
// the per-tile compute (T5, attn-positive).
// Diagonal masking: qg<w fully masked (skip), qg==w partial (lk*4+r>lm),
// qg>w unmasked.
__global__ __launch_bounds__(256) void k_attn(
    const US* __restrict__ qbuf, const US* __restrict__ kbuf,
    const US* __restrict__ vtbuf, US* __restrict__ ctx) {
  __shared__ __align__(16) char smem[32768];
  US* KsB = (US*)smem;             // [2][4096] US (16KB): K double buffer
  US* VsB = (US*)(smem + 16384);   // [2][4096] US (16KB): V double buffer
  int tid = threadIdx.x;
  int w = tid >> 6, lane = tid & 63;
  int lm = lane & 15, lk = lane >> 4;
  int bl = blockIdx.x;            // 1024 blocks
  int xcd = bl & 7, g = bl >> 3;  // g 0..127
  int bh = (g & 3) * 8 + xcd;     // 4 bh per XCD -> working set ~2MB < 4MB L2
  int q4 = g >> 2;                // 0..31
  int rnd = q4 >> 3, qq = q4 & 7;
  int s = (rnd == 0) ? 31 - qq : (rnd == 1) ? qq : (rnd == 2) ? 23 - qq : 8 + qq;
  int nt = s + 1;                 // 64-key tiles (can be 1)

  const US* kbase = kbuf + (size_t)bh * SEQ * DHEAD;
  const US* vtb = vtbuf + (size_t)bh * DHEAD * SEQ;

  // Q fragments for all 4 q-groups of this strip (each wave needs all 64 q-rows)
  short8 qf[4][2];
#pragma unroll
  for (int qg = 0; qg < 4; ++qg) {
    const US* qr = qbuf + ((size_t)bh * SEQ + s * 64 + qg * 16 + lm) * DHEAD + lk * 8;
    qf[qg][0] = *(const short8*)(qr);
    qf[qg][1] = *(const short8*)(qr + 32);
  }

  // staging: 16 async16 units (8 K + 8 V), 4 per wave, source-side XOR swizzle
  int swz = ((lane & 7) ^ (lane >> 3)) * 8;
  const US* gsrc[4];
  US* ldst[4];
  int step[4];
#pragma unroll
  for (int j = 0; j < 4; ++j) {
    int u = w + 4 * j;
    if (u < 8) {
      gsrc[j] = kbase + (size_t)(u * 8 + (lane >> 3)) * DHEAD + swz;
      ldst[j] = KsB + u * 512 + lane * 8;
      step[j] = 64 * DHEAD;
    } else {
      int i = u - 8;
      gsrc[j] = vtb + (size_t)(i * 8 + (lane >> 3)) * SEQ + swz;
      ldst[j] = VsB + i * 512 + lane * 8;
      step[j] = 64;
    }
  }

  // fragment-read offsets (bytes), swizzle-corrected; kg is fixed = w
  int xorv = lm & 7;
  int ck0 = ((lk) ^ xorv) * 16;
  int ck1 = ((4 + lk) ^ xorv) * 16;
  int cvw = (((w * 2 + (lk >> 1)) ^ xorv) * 16) + (lk & 1) * 8;

  f32x4 o[4][4];  // [dg][qg]; lane (lm,lk) reg r -> O[q=qg*16+lm][d=dg*16+lk*4+r]
#pragma unroll
  for (int dg = 0; dg < 4; ++dg)
#pragma unroll
    for (int qg = 0; qg < 4; ++qg) o[dg][qg] = (f32x4){0.f, 0.f, 0.f, 0.f};
  float racc[4] = {0.f, 0.f, 0.f, 0.f};  // partial rowsums (keys of this wave's lk slice)

  // prologue: tile0 -> buf0, (tile1 -> buf1 if it exists)
#pragma unroll
  for (int j = 0; j < 4; ++j) { async16(gsrc[j], ldst[j]); gsrc[j] += step[j]; }
  if (nt > 1) {
#pragma unroll
    for (int j = 0; j < 4; ++j) { async16(gsrc[j], ldst[j] + 4096); gsrc[j] += step[j]; }
  }

  for (int t = 0; t < nt; ++t) {
    if (t + 1 < nt) asm volatile("s_waitcnt vmcnt(4)" ::: "memory");
    else            asm volatile("s_waitcnt vmcnt(0)" ::: "memory");
    __builtin_amdgcn_s_barrier();
    asm volatile("" ::: "memory");

    const char* Kc = (const char*)(KsB + (t & 1) * 4096);
    const char* Vc = (const char*)(VsB + (t & 1) * 4096);
    bool diag = (t == s);

    __builtin_amdgcn_s_setprio(1);
    // this wave's K slice (kg = w): 16 keys x 64 d
    const char* kr = Kc + (w * 16 + lm) * 128;
    short8 ka0 = *(const short8*)(kr + ck0);
    short8 ka1 = *(const short8*)(kr + ck1);
    // this wave's V slice: 4 dg fragments, each [16 d][16 k]
    short4v va[4];
#pragma unroll
    for (int dg = 0; dg < 4; ++dg)
      va[dg] = *(const short4v*)(Vc + lm * 128 + cvw + dg * 2048);

#pragma unroll
    for (int qg = 0; qg < 4; ++qg) {
      if (diag && qg < w) continue;  // wave-uniform: keys all above these q-rows
      f32x4 st = (f32x4){0.f, 0.f, 0.f, 0.f};
      st = mfma16(ka0, qf[qg][0], st);
      st = mfma16(ka1, qf[qg][1], st);
      bool pm = diag && (qg == w);
      uint32_t ue[4];
#pragma unroll
      for (int r = 0; r < 4; ++r) {
        float v = st[r];                       // log2 domain (Q pre-scaled)
        if (pm && (lk * 4 + r > lm)) v = -INFINITY;
        union { float f; uint32_t u; } cv2;
        cv2.f = exp2f(v);
        ue[r] = cv2.u + 0x8000u;               // bf16 bias-round; -inf -> +0
      }
      // rowsum of the SAME rounded values the MFMA will consume
      union { float f; uint32_t u; } b0, b1, b2, b3;
      b0.u = ue[0] & 0xFFFF0000u; b1.u = ue[1] & 0xFFFF0000u;
      b2.u = ue[2] & 0xFFFF0000u; b3.u = ue[3] & 0xFFFF0000u;
      racc[qg] += (b0.f + b1.f) + (b2.f + b3.f);
      union { short4v s4; uint32_t u[2]; } pk;
      pk.u[0] = __builtin_amdgcn_perm(ue[1], ue[0], 0x07060302u);
      pk.u[1] = __builtin_amdgcn_perm(ue[3], ue[2], 0x07060302u);
#pragma unroll
      for (int dg = 0; dg < 4; ++dg)
        o[dg][qg] = mfma16k16(va[dg], pk.s4, o[dg][qg]);
    }
    __builtin_amdgcn_s_setprio(0);

    asm volatile("" ::: "memory");
    __builtin_amdgcn_s_barrier();
    asm volatile("" ::: "memory");
    if (t + 2 < nt) {
#pragma unroll
      for (int j = 0; j < 4; ++j) {
        async16(gsrc[j], ldst[j] + (t & 1) * 4096);
        gsrc[j] += step[j];
      }
    }
  }

  // ---- cross-wave reduction: wave w finalizes qg == w ----
  // red region: [qg][c][dgL][lane] f32x4, (qg*3+c)*128 + dgL*64 + lane; 24KB
  // racc region at +24KB: [w][lane] f32x4 (4KB)
  f32x4* red4 = (f32x4*)smem;
  f32x4* r4 = (f32x4*)(smem + 24 * 1024);
#pragma unroll
  for (int h = 0; h < 2; ++h) {
#pragma unroll
    for (int qg = 0; qg < 4; ++qg) {
      if (qg != w) {
        int c = (w < qg) ? w : w - 1;
        red4[(qg * 3 + c) * 128 + 0 * 64 + lane] = o[h * 2 + 0][qg];
        red4[(qg * 3 + c) * 128 + 1 * 64 + lane] = o[h * 2 + 1][qg];
      }
    }
    if (h == 0) r4[w * 64 + lane] = (f32x4){racc[0], racc[1], racc[2], racc[3]};
    __syncthreads();
#pragma unroll
    for (int qg = 0; qg < 4; ++qg) {
      if (qg == w) {
#pragma unroll
        for (int c = 0; c < 3; ++c) {
          o[h * 2 + 0][qg] += red4[(qg * 3 + c) * 128 + 0 * 64 + lane];
          o[h * 2 + 1][qg] += red4[(qg * 3 + c) * 128 + 1 * 64 + lane];
        }
      }
    }
    __syncthreads();
  }
  // rowsum for q = w*16+lm: sum racc component w over 4 waves, then over lk
  const float* rr = (const float*)(smem + 24 * 1024);
  float myrs = rr[(0 * 64 + lane) * 4 + w] + rr[(1 * 64 + lane) * 4 + w] +
               rr[(2 * 64 + lane) * 4 + w] + rr[(3 * 64 + lane) * 4 + w];
  myrs += __shfl_xor(myrs, 16);
  myrs += __shfl_xor(myrs, 32);
  float inv = 1.f / myrs;

  US* crow = ctx + ((size_t)(bh >> 4) * SEQ + s * 64 + w * 16 + lm) * NOUTF + (bh & 15) * DHEAD;
#pragma unroll
  for (int qg = 0; qg < 4; ++qg) {
    if (qg == w) {
#pragma unroll
      for (int dg = 0; dg < 4; ++dg) {
        union { short4v s4; uint32_t u[2]; } pk;
        pk.u[0] = (uint32_t)f2bf(o[dg][qg][0] * inv) | ((uint32_t)f2bf(o[dg][qg][1] * inv) << 16);
        pk.u[1] = (uint32_t)f2bf(o[dg][qg][2] * inv) | ((uint32_t)f2bf(o[dg][qg][3] * inv) << 16);
        *(short4v*)(crow + dg * 16 + lk * 4) = pk.s4;
      }
    }
  }
}

// ---------------- out GEMM: 128x64 tile, fused bias, fp32 out ------
__global__ __launch_bounds__(256) void k_gemm_out(
    const US* __restrict__ A, const US* __restrict__ Bt,
    const float* __restrict__ bias, float* __restrict__ out) {
  __shared__ US As[128 * 32];
  __shared__ US Bs[64 * 32];
  int tid = threadIdx.x;
  int wave = tid >> 6, lane = tid & 63, lm = lane & 15, lk = lane >> 4;
  int mbase = blockIdx.y * 128, nbase = blockIdx.x * 64;

  f32x4 acc[2][4];
#pragma unroll
  for (int i = 0; i < 2; ++i)
#pragma unroll
    for (int j = 0; j < 4; ++j) acc[i][j] = (f32x4){0.f, 0.f, 0.f, 0.f};

  const US* ga = A + (size_t)(mbase + (tid >> 2)) * NOUTF + (tid & 3) * 8;
  const US* gb = Bt + (size_t)(nbase + (tid >> 2)) * NOUTF + (tid & 3) * 8;
  US* la = As + tid * 8;
  US* lb = Bs + tid * 8;

  for (int kt = 0; kt < NOUTF / 32; ++kt) {
    int ko = kt * 32;
    async16(ga + ko, la);
    async16(ga + ko + (size_t)64 * NOUTF, la + 64 * 32);
    async16(gb + ko, lb);
    __syncthreads();
    short8 a[2], b[4];
#pragma unroll
    for (int i = 0; i < 2; ++i)
      a[i] = *(const short8*)(As + (wave * 32 + i * 16 + lm) * 32 + lk * 8);
#pragma unroll
    for (int j = 0; j < 4; ++j)
      b[j] = *(const short8*)(Bs + (j * 16 + lm) * 32 + lk * 8);
#pragma unroll
    for (int i = 0; i < 2; ++i)
#pragma unroll
      for (int j = 0; j < 4; ++j) acc[i][j] = mfma16(a[i], b[j], acc[i][j]);
    __syncthreads();
  }

#pragma unroll
  for (int j = 0; j < 4; ++j) {
    int col = nbase + j * 16 + lm;
    float bv = bias[col];
#pragma unroll
    for (int i = 0; i < 2; ++i)
#pragma unroll
      for (int r = 0; r < 4; ++r) {
        int row = mbase + wave * 32 + i * 16 + lk * 4 + r;
        out[(size_t)row * NOUTF + col] = acc[i][j][r] + bv;
      }
  }
}

extern "C" void kernel_launch(void* const* d_in, const int* in_sizes, int n_in,
                              void* d_out, int out_size, void* d_ws, size_t ws_size,
                              hipStream_t stream) {
  const float* y    = (const float*)d_in[0];
  const float* Wqkv = (const float*)d_in[1];
  const float* Wff  = (const float*)d_in[2];
  const float* bff  = (const float*)d_in[3];
  float* out = (float*)d_out;

  char* ws = (char*)d_ws;
  US* ybf   = (US*)(ws);                 // [0,8M)  y bf16; dead after qkv
  US* ctx   = (US*)(ws);                 // [0,8M)  reuse for ctx
  US* wqkvt = (US*)(ws + (8u << 20));    // [8,14M)
  US* wfft  = (US*)(ws + (14u << 20));   // [14,16M)
  US* qbuf  = (US*)(ws + (16u << 20));   // [16,24M)
  US* kbuf  = (US*)(ws + (24u << 20));   // [24,32M)
  US* vbuf  = (US*)(ws + (32u << 20));   // [32,40M) dead after vtrans
  US* vtbuf = (US*)(ws + (40u << 20));   // [40,48M)

  k_convert<<<MTOT * NINF / 4 / 256, 256, 0, stream>>>(y, ybf, MTOT * NINF / 4);
  k_wtrans<<<dim3(128, 32), dim3(32, 8), 0, stream>>>(Wqkv, Wff, wqkvt, wfft);
  k_gemm_qkv<<<dim3(N3 / 128, MTOT / 128), 256, 0, stream>>>(ybf, wqkvt, qbuf, kbuf, vbuf);
  k_vtrans<<<dim3(DHEAD / 32, SEQ / 32, BATCH * NHEADS), dim3(32, 8), 0, stream>>>(vbuf, vtbuf);
  k_attn<<<dim3(1024), 256, 0, stream>>>(qbuf, kbuf, vtbuf, ctx);
  k_gemm_out<<<dim3(NOUTF / 64, MTOT / 128), 256, 0, stream>>>(ctx, wfft, bff, out);
}

// Round 5
// 181.161 us; speedup vs baseline: 1.1044x; 1.1044x over previous
//
#include <hip/hip_runtime.h>
#include <stdint.h>

#define NHEADS 16
#define DHEAD 64
#define SEQ 2048
#define BATCH 2
#define NINF 1024
#define NOUTF 1024
#define N3 3072
#define MTOT 4096  // BATCH*SEQ

typedef unsigned short US;
typedef __attribute__((ext_vector_type(8))) short short8;
typedef __attribute__((ext_vector_type(4))) short short4v;
typedef __attribute__((ext_vector_type(4))) float f32x4;

__device__ inline US f2bf(float f) {
  union { float f; unsigned u; } v; v.f = f;
  unsigned r = v.u + 0x7fffu + ((v.u >> 16) & 1u);
  return (US)(r >> 16);
}

__device__ inline f32x4 mfma16(short8 a, short8 b, f32x4 c) {
  return __builtin_amdgcn_mfma_f32_16x16x32_bf16(a, b, c, 0, 0, 0);
}

__device__ inline f32x4 mfma16k16(short4v a, short4v b, f32x4 c) {
  return __builtin_amdgcn_mfma_f32_16x16x16bf16_1k(a, b, c, 0, 0, 0);
}

__device__ inline void async16(const US* g, US* l) {
  __builtin_amdgcn_global_load_lds(
      (const __attribute__((address_space(1))) unsigned int*)g,
      (__attribute__((address_space(3))) unsigned int*)l, 16, 0, 0);
}

// fp32 -> bf16, 4 elements/thread
__global__ void k_convert(const float* __restrict__ src, US* __restrict__ dst, int n4) {
  int i = blockIdx.x * blockDim.x + threadIdx.x;
  if (i >= n4) return;
  float4 v = ((const float4*)src)[i];
  ushort4 o;
  o.x = f2bf(v.x); o.y = f2bf(v.y); o.z = f2bf(v.z); o.w = f2bf(v.w);
  ((ushort4*)dst)[i] = o;
}

// merged weight transpose: Wqkv [1024][3072] and Wff [1024][1024] -> bf16 [C][1024]
__global__ void k_wtrans(const float* __restrict__ Wqkv, const float* __restrict__ Wff,
                         US* __restrict__ dq, US* __restrict__ df) {
  __shared__ float tile[32][33];
  int bxi = blockIdx.x;
  const float* src; US* dst; int C;
  if (bxi < 96) { src = Wqkv; dst = dq; C = N3; }
  else          { src = Wff;  dst = df; C = NOUTF; bxi -= 96; }
  int bx = bxi * 32, by = blockIdx.y * 32;
  int tx = threadIdx.x, ty = threadIdx.y;
  for (int i = 0; i < 32; i += 8)
    tile[ty + i][tx] = src[(size_t)(by + ty + i) * C + bx + tx];
  __syncthreads();
  for (int i = 0; i < 32; i += 8)
    dst[(size_t)(bx + ty + i) * 1024 + by + tx] = f2bf(tile[tx][ty + i]);
}

// per-bh bf16 transpose: vbuf [bh][2048][64] -> vtbuf [bh][64][2048]
__global__ void k_vtrans(const US* __restrict__ src, US* __restrict__ dst) {
  __shared__ US tile[32][33];
  int bh = blockIdx.z;
  int bx = blockIdx.x * 32;  // d
  int by = blockIdx.y * 32;  // s
  int tx = threadIdx.x, ty = threadIdx.y;
  const US* s0 = src + (size_t)bh * SEQ * DHEAD;
  US* d0 = dst + (size_t)bh * DHEAD * SEQ;
  for (int i = 0; i < 32; i += 8)
    tile[ty + i][tx] = s0[(size_t)(by + ty + i) * DHEAD + bx + tx];
  __syncthreads();
  for (int i = 0; i < 32; i += 8)
    d0[(size_t)(bx + ty + i) * SEQ + by + tx] = tile[tx][ty + i];
}

// ---------------- qkv GEMM: 128x128 tile, m97 structure ----------------
// Q is pre-scaled by log2(e)/sqrt(DHEAD) so attention scores are directly
// exp2 exponents (deletes one v_mul per score in k_attn).
__global__ __launch_bounds__(256) void k_gemm_qkv(
    const US* __restrict__ A,   // [MTOT][NINF]
    const US* __restrict__ Bt,  // [N3][NINF]
    US* __restrict__ qbuf, US* __restrict__ kbuf, US* __restrict__ vbuf) {
  __shared__ US As[128 * 32];
  __shared__ US Bs[128 * 32];
  int tid = threadIdx.x;
  int wave = tid >> 6, lane = tid & 63, lm = lane & 15, lk = lane >> 4;
  int wm = wave >> 1, wn = wave & 1;
  int mbase = blockIdx.y * 128, nbase = blockIdx.x * 128;

  f32x4 acc[4][4];
#pragma unroll
  for (int i = 0; i < 4; ++i)
#pragma unroll
    for (int j = 0; j < 4; ++j) acc[i][j] = (f32x4){0.f, 0.f, 0.f, 0.f};

  const US* ga = A + (size_t)(mbase + (tid >> 2)) * NINF + (tid & 3) * 8;
  const US* gb = Bt + (size_t)(nbase + (tid >> 2)) * NINF + (tid & 3) * 8;
  US* la = As + tid * 8;
  US* lb = Bs + tid * 8;

  for (int kt = 0; kt < NINF / 32; ++kt) {
    int ko = kt * 32;
    async16(ga + ko, la);
    async16(ga + ko + (size_t)64 * NINF, la + 64 * 32);
    async16(gb + ko, lb);
    async16(gb + ko + (size_t)64 * NINF, lb + 64 * 32);
    __syncthreads();
    short8 a[4], b[4];
#pragma unroll
    for (int i = 0; i < 4; ++i)
      a[i] = *(const short8*)(As + (wm * 64 + i * 16 + lm) * 32 + lk * 8);
#pragma unroll
    for (int j = 0; j < 4; ++j)
      b[j] = *(const short8*)(Bs + (wn * 64 + j * 16 + lm) * 32 + lk * 8);
#pragma unroll
    for (int i = 0; i < 4; ++i)
#pragma unroll
      for (int j = 0; j < 4; ++j) acc[i][j] = mfma16(a[i], b[j], acc[i][j]);
    __syncthreads();
  }

  int which = nbase >> 10;  // 0=q 1=k 2=v (uniform per block)
  US* dsts = (which == 0) ? qbuf : (which == 1) ? kbuf : vbuf;
  float sc = (which == 0) ? 0.18033688011112042f : 1.f;  // log2(e)/8 folded into Q
#pragma unroll
  for (int j = 0; j < 4; ++j) {
    int col = nbase + wn * 64 + j * 16 + lm;
    int hh = (col & 1023) >> 6;
    int d = col & 63;
#pragma unroll
    for (int i = 0; i < 4; ++i) {
#pragma unroll
      for (int r = 0; r < 4; ++r) {
        int row = mbase + wm * 64 + i * 16 + lk * 4 + r;
        int bb = row >> 11;
        int s = row & (SEQ - 1);
        int bh = bb * NHEADS + hh;
        dsts[((size_t)bh * SEQ + s) * DHEAD + d] = f2bf(acc[i][j][r] * sc);
      }
    }
  }
}

// ---------------- attention v10: hybrid 32q x 32k wave split ----------------
// v9 post-mortem: full key-split (wave = all 64 q x 16 keys) regressed
// 45.7->64.8us despite 3.6x conflict cut: o[4][4]+qf[4][2]=96 VGPRs of pure
// state wrecked scheduling, single read-burst lost v8's read/compute
// interleave, setprio convoyed barrier-locked blocks (m190 precedent).
// v10 = v8 verbatim EXCEPT the wave decomposition: wave w = (q-half h=w>>1,
// key-half kh=w&1) owns 2 q-groups x 2 key-groups:
//  - LDS reads halved vs v8 (8KB/wave/tile): tests LDS contention cleanly
//  - state o[4][2]+qf[2][2]+lacc[2] = 56 regs (~84 total, no pressure cliff)
//  - v8 body shape kept (per-kg read then compute), NO setprio,
//    rowsum on ones-MFMA (proven), same MFMA/exp2 counts as v8
//  - keys split across wave pairs => O/rowsum partials combine by ADDITION
//    (no running max in this softmax), one 2-wave LDS combine at the end.
// Diagonal: kg>qg skip, kg==qg partial (lk*4+r>lm), kg<qg full.
// Keeps v8 balanced rounds, depth-2 dbuf + counted vmcnt(4), staging, swizzle.
__global__ __launch_bounds__(256) void k_attn(
    const US* __restrict__ qbuf, const US* __restrict__ kbuf,
    const US* __restrict__ vtbuf, US* __restrict__ ctx) {
  __shared__ US Ks[2][64 * 64];
  __shared__ US Vs[2][64 * 64];
  int tid = threadIdx.x;
  int w = tid >> 6, lane = tid & 63;
  int lm = lane & 15, lk = lane >> 4;
  int h = w >> 1;   // q-half: qg in {2h, 2h+1}
  int kh = w & 1;   // key-half: kg in {2kh, 2kh+1}
  int bl = blockIdx.x;            // 1024 blocks
  int xcd = bl & 7, g = bl >> 3;  // g 0..127
  int bh = (g & 3) * 8 + xcd;     // 4 bh per XCD -> working set ~2MB < 4MB L2
  int q4 = g >> 2;                // 0..31
  int rnd = q4 >> 3, qq = q4 & 7;
  int s = (rnd == 0) ? 31 - qq : (rnd == 1) ? qq : (rnd == 2) ? 23 - qq : 8 + qq;
  int nt = s + 1;                 // 64-key tiles (can be 1)

  const US* kbase = kbuf + (size_t)bh * SEQ * DHEAD;
  const US* vtb = vtbuf + (size_t)bh * DHEAD * SEQ;

  // Q fragments for this wave's 2 q-groups
  short8 qf[2][2];
#pragma unroll
  for (int i = 0; i < 2; ++i) {
    const US* qr = qbuf + ((size_t)bh * SEQ + s * 64 + (2 * h + i) * 16 + lm) * DHEAD + lk * 8;
    qf[i][0] = *(const short8*)(qr);
    qf[i][1] = *(const short8*)(qr + 32);
  }

  // staging: 16 async16 units (8 K + 8 V), 4 per wave, source-side XOR swizzle
  int swz = ((lane & 7) ^ (lane >> 3)) * 8;
  const US* gsrc[4];
  US* ldst[4];
  int step[4];
#pragma unroll
  for (int j = 0; j < 4; ++j) {
    int u = w + 4 * j;
    if (u < 8) {
      gsrc[j] = kbase + (size_t)(u * 8 + (lane >> 3)) * DHEAD + swz;
      ldst[j] = &Ks[0][0] + u * 512 + lane * 8;
      step[j] = 64 * DHEAD;
    } else {
      int i = u - 8;
      gsrc[j] = vtb + (size_t)(i * 8 + (lane >> 3)) * SEQ + swz;
      ldst[j] = &Vs[0][0] + i * 512 + lane * 8;
      step[j] = 64;
    }
  }

  // fragment-read offsets (bytes), swizzle-corrected
  int xorv = lm & 7;
  int ck0 = ((lk) ^ xorv) * 16;
  int ck1 = ((4 + lk) ^ xorv) * 16;
  int cv[2];
#pragma unroll
  for (int kgi = 0; kgi < 2; ++kgi) {
    int kg = 2 * kh + kgi;
    cv[kgi] = (((kg * 2 + (lk >> 1)) ^ xorv) * 16) + (lk & 1) * 8;
  }

  f32x4 o[4][2];   // [dg][i]; lane (lm,lk) reg r -> O[q=(2h+i)*16+lm][d=dg*16+lk*4+r]
#pragma unroll
  for (int dg = 0; dg < 4; ++dg)
#pragma unroll
    for (int i = 0; i < 2; ++i) o[dg][i] = (f32x4){0.f, 0.f, 0.f, 0.f};
  f32x4 lacc[2] = {(f32x4){0.f, 0.f, 0.f, 0.f}, (f32x4){0.f, 0.f, 0.f, 0.f}};
  const short4v kones = {(short)0x3F80, (short)0x3F80, (short)0x3F80, (short)0x3F80};

  // prologue: tile0 -> buf0, (tile1 -> buf1 if it exists)
#pragma unroll
  for (int j = 0; j < 4; ++j) { async16(gsrc[j], ldst[j]); gsrc[j] += step[j]; }
  if (nt > 1) {
#pragma unroll
    for (int j = 0; j < 4; ++j) { async16(gsrc[j], ldst[j] + 4096); gsrc[j] += step[j]; }
  }

  for (int t = 0; t < nt; ++t) {
    if (t + 1 < nt) asm volatile("s_waitcnt vmcnt(4)" ::: "memory");
    else            asm volatile("s_waitcnt vmcnt(0)" ::: "memory");
    __builtin_amdgcn_s_barrier();
    asm volatile("" ::: "memory");

    const char* Kc = (const char*)Ks + (t & 1) * 8192;
    const char* Vc = (const char*)Vs + (t & 1) * 8192;
    bool diag = (t == s);

#pragma unroll
    for (int kgi = 0; kgi < 2; ++kgi) {
      int kg = 2 * kh + kgi;
      const char* kr = Kc + (kg * 16 + lm) * 128;
      short8 ka0 = *(const short8*)(kr + ck0);
      short8 ka1 = *(const short8*)(kr + ck1);
      const char* vr = Vc + lm * 128 + cv[kgi];
      short4v va[4];
#pragma unroll
      for (int dg = 0; dg < 4; ++dg)
        va[dg] = *(const short4v*)(vr + dg * 2048);
#pragma unroll
      for (int i = 0; i < 2; ++i) {
        int qg = 2 * h + i;
        if (diag && kg > qg) continue;   // wave-uniform: keys entirely above these q-rows
        f32x4 st = (f32x4){0.f, 0.f, 0.f, 0.f};
        st = mfma16(ka0, qf[i][0], st);
        st = mfma16(ka1, qf[i][1], st);
        bool pm = diag && (kg == qg);
        uint32_t ue[4];
#pragma unroll
        for (int r = 0; r < 4; ++r) {
          float v = st[r];                       // log2 domain (Q pre-scaled)
          if (pm && (lk * 4 + r > lm)) v = -INFINITY;
          union { float f; uint32_t u; } cv2;
          cv2.f = exp2f(v);
          ue[r] = cv2.u + 0x8000u;               // bf16 bias-round; -inf -> +0
        }
        union { short4v s4; uint32_t u[2]; } pk;
        pk.u[0] = __builtin_amdgcn_perm(ue[1], ue[0], 0x07060302u);
        pk.u[1] = __builtin_amdgcn_perm(ue[3], ue[2], 0x07060302u);
        lacc[i] = mfma16k16(kones, pk.s4, lacc[i]);   // row-sums on the MFMA pipe
#pragma unroll
        for (int dg = 0; dg < 4; ++dg)
          o[dg][i] = mfma16k16(va[dg], pk.s4, o[dg][i]);
      }
    }

    asm volatile("" ::: "memory");
    __builtin_amdgcn_s_barrier();
    asm volatile("" ::: "memory");
    if (t + 2 < nt) {
#pragma unroll
      for (int j = 0; j < 4; ++j) {
        async16(gsrc[j], ldst[j] + (t & 1) * 4096);
        gsrc[j] += step[j];
      }
    }
  }

  // ---- cross-wave combine: kh=1 exports partials, kh=0 adds + stores ----
  // (main loop's final s_barrier has completed: all LDS reads done, safe to reuse)
  // red4 (16KB, in Ks): [(h*2+i)*4+dg][lane]; rl4 (4KB, in Vs): [(h*2+i)][lane]
  f32x4* red4 = (f32x4*)&Ks[0][0];
  f32x4* rl4 = (f32x4*)&Vs[0][0];
  if (kh == 1) {
#pragma unroll
    for (int i = 0; i < 2; ++i) {
#pragma unroll
      for (int dg = 0; dg < 4; ++dg)
        red4[((h * 2 + i) * 4 + dg) * 64 + lane] = o[dg][i];
      rl4[(h * 2 + i) * 64 + lane] = lacc[i];
    }
  }
  __syncthreads();
  if (kh == 0) {
#pragma unroll
    for (int i = 0; i < 2; ++i) {
      f32x4 ls = lacc[i] + rl4[(h * 2 + i) * 64 + lane];
      float inv = 1.f / ls[0];   // rowsum identical across regs/lk groups
      US* crow = ctx + ((size_t)(bh >> 4) * SEQ + s * 64 + (2 * h + i) * 16 + lm) * NOUTF +
                 (bh & 15) * DHEAD;
#pragma unroll
      for (int dg = 0; dg < 4; ++dg) {
        f32x4 oo = o[dg][i] + red4[((h * 2 + i) * 4 + dg) * 64 + lane];
        union { short4v s4; uint32_t u[2]; } pk;
        pk.u[0] = (uint32_t)f2bf(oo[0] * inv) | ((uint32_t)f2bf(oo[1] * inv) << 16);
        pk.u[1] = (uint32_t)f2bf(oo[2] * inv) | ((uint32_t)f2bf(oo[3] * inv) << 16);
        *(short4v*)(crow + dg * 16 + lk * 4) = pk.s4;
      }
    }
  }
}

// ---------------- out GEMM: 128x64 tile, fused bias, fp32 out ------
__global__ __launch_bounds__(256) void k_gemm_out(
    const US* __restrict__ A, const US* __restrict__ Bt,
    const float* __restrict__ bias, float* __restrict__ out) {
  __shared__ US As[128 * 32];
  __shared__ US Bs[64 * 32];
  int tid = threadIdx.x;
  int wave = tid >> 6, lane = tid & 63, lm = lane & 15, lk = lane >> 4;
  int mbase = blockIdx.y * 128, nbase = blockIdx.x * 64;

  f32x4 acc[2][4];
#pragma unroll
  for (int i = 0; i < 2; ++i)
#pragma unroll
    for (int j = 0; j < 4; ++j) acc[i][j] = (f32x4){0.f, 0.f, 0.f, 0.f};

  const US* ga = A + (size_t)(mbase + (tid >> 2)) * NOUTF + (tid & 3) * 8;
  const US* gb = Bt + (size_t)(nbase + (tid >> 2)) * NOUTF + (tid & 3) * 8;
  US* la = As + tid * 8;
  US* lb = Bs + tid * 8;

  for (int kt = 0; kt < NOUTF / 32; ++kt) {
    int ko = kt * 32;
    async16(ga + ko, la);
    async16(ga + ko + (size_t)64 * NOUTF, la + 64 * 32);
    async16(gb + ko, lb);
    __syncthreads();
    short8 a[2], b[4];
#pragma unroll
    for (int i = 0; i < 2; ++i)
      a[i] = *(const short8*)(As + (wave * 32 + i * 16 + lm) * 32 + lk * 8);
#pragma unroll
    for (int j = 0; j < 4; ++j)
      b[j] = *(const short8*)(Bs + (j * 16 + lm) * 32 + lk * 8);
#pragma unroll
    for (int i = 0; i < 2; ++i)
#pragma unroll
      for (int j = 0; j < 4; ++j) acc[i][j] = mfma16(a[i], b[j], acc[i][j]);
    __syncthreads();
  }

#pragma unroll
  for (int j = 0; j < 4; ++j) {
    int col = nbase + j * 16 + lm;
    float bv = bias[col];
#pragma unroll
    for (int i = 0; i < 2; ++i)
#pragma unroll
      for (int r = 0; r < 4; ++r) {
        int row = mbase + wave * 32 + i * 16 + lk * 4 + r;
        out[(size_t)row * NOUTF + col] = acc[i][j][r] + bv;
      }
  }
}

extern "C" void kernel_launch(void* const* d_in, const int* in_sizes, int n_in,
                              void* d_out, int out_size, void* d_ws, size_t ws_size,
                              hipStream_t stream) {
  const float* y    = (const float*)d_in[0];
  const float* Wqkv = (const float*)d_in[1];
  const float* Wff  = (const float*)d_in[2];
  const float* bff  = (const float*)d_in[3];
  float* out = (float*)d_out;

  char* ws = (char*)d_ws;
  US* ybf   = (US*)(ws);                 // [0,8M)  y bf16; dead after qkv
  US* ctx   = (US*)(ws);                 // [0,8M)  reuse for ctx
  US* wqkvt = (US*)(ws + (8u << 20));    // [8,14M)
  US* wfft  = (US*)(ws + (14u << 20));   // [14,16M)
  US* qbuf  = (US*)(ws + (16u << 20));   // [16,24M)
  US* kbuf  = (US*)(ws + (24u << 20));   // [24,32M)
  US* vbuf  = (US*)(ws + (32u << 20));   // [32,40M) dead after vtrans
  US* vtbuf = (US*)(ws + (40u << 20));   // [40,48M)

  k_convert<<<MTOT * NINF / 4 / 256, 256, 0, stream>>>(y, ybf, MTOT * NINF / 4);
  k_wtrans<<<dim3(128, 32), dim3(32, 8), 0, stream>>>(Wqkv, Wff, wqkvt, wfft);
  k_gemm_qkv<<<dim3(N3 / 128, MTOT / 128), 256, 0, stream>>>(ybf, wqkvt, qbuf, kbuf, vbuf);
  k_vtrans<<<dim3(DHEAD / 32, SEQ / 32, BATCH * NHEADS), dim3(32, 8), 0, stream>>>(vbuf, vtbuf);
  k_attn<<<dim3(1024), 256, 0, stream>>>(qbuf, kbuf, vtbuf, ctx);
  k_gemm_out<<<dim3(NOUTF / 64, MTOT / 128), 256, 0, stream>>>(ctx, wfft, bff, out);
}